// Round 1
// baseline (547.918 us; speedup 1.0000x reference)
//
#include <hip/hip_runtime.h>
#include <stdint.h>

// FeatsInitLayer fused kernel for MI355X (gfx950)
//
// Reference:
//   x    = emb_W[coords]                                  [N,64]
//   rbf0 = swish(rbf @ W_rbf0 + b_rbf0)                   [E,64]
//   e1   = swish([x_i | x_j | rbf0] @ W_lin + b_lin)      [E,64]
//   e2   = (rbf @ W_rbf1) * e1                            [E,64]
//
// Algebra: cat@W_lin = x_i@W1 + x_j@W2 + rbf0@W3  (W_lin = [W1;W2;W3])
//   emb1[c] = emb_W[c]@W1, emb2[c] = emb_W[c]@W2 + b_lin  (95x64 tables)
// so per edge only rbf@[W_rbf0|W_rbf1] (K=16) and rbf0@W3 (K=64) remain,
// done with mfma_f32_16x16x32_bf16 (16 edges per wave-tile).

#define N_NODES 100000
#define N_EDGES 800000
#define H_NF 64
#define VOCAB 95
#define NTILES (N_EDGES / 16)   // 50000

typedef __attribute__((ext_vector_type(8))) short short8;
typedef __attribute__((ext_vector_type(4))) float f32x4;

// ---- ws layout in u16 units ----
#define TAB_STRIDE 66                   // 66 u16 per row: bank-rotates gathers
#define TAB2_OFF   (VOCAB * TAB_STRIDE) // 6270
#define TAB_U16    (2 * VOCAB * TAB_STRIDE)  // 12540
#define TAB_U16_PAD 12544               // pad to 16B multiple
#define B0_OFF     TAB_U16_PAD          // 8 tiles * 64 lanes * 8 bf16 = 4096
#define W3_OFF     (TAB_U16_PAD + 4096) // 8 frags * 64 * 8 = 4096

__device__ __forceinline__ unsigned short f2bf(float x) {
  uint32_t u = __float_as_uint(x);
  return (unsigned short)((u + 0x7FFFu + ((u >> 16) & 1u)) >> 16);  // RNE
}
__device__ __forceinline__ float bf2f(unsigned short b) {
  return __uint_as_float(((uint32_t)b) << 16);
}
__device__ __forceinline__ float swish_f(float x) {
  return x * __builtin_amdgcn_rcpf(1.0f + __expf(-x));
}

// ---------------- prep: tables + bf16 weight fragments into ws ----------------
__global__ void feats_prep(const float* __restrict__ emb_W,
                           const float* __restrict__ W_rbf0,
                           const float* __restrict__ b_rbf0,
                           const float* __restrict__ W_lin,
                           const float* __restrict__ b_lin,
                           const float* __restrict__ W_rbf1,
                           unsigned short* __restrict__ ws16) {
  const int b = blockIdx.x, t = threadIdx.x;  // 64 threads/block
  if (b < VOCAB) {
    const int c = b, h = t;
    float e1 = 0.f, e2 = b_lin[h];
    for (int k = 0; k < 64; ++k) {
      const float w = emb_W[c * 64 + k];
      e1 += w * W_lin[k * 64 + h];            // W1 rows 0..63   (x_i side)
      e2 += w * W_lin[(64 + k) * 64 + h];     // W2 rows 64..127 (x_j side)
    }
    ws16[c * TAB_STRIDE + h] = f2bf(e1);
    ws16[TAB2_OFF + c * TAB_STRIDE + h] = f2bf(e2);
  } else if (b == VOCAB) {
    // B0 fragments: B0[k][n], k<16: [W_rbf0 | W_rbf1]; k==16: [b_rbf0 | 0]; else 0
    // frag layout: [ntile t][lane l][i]  -> element B0[(l>>4)*8+i][t*16+(l&15)]
    for (int idx = t; idx < 4096; idx += 64) {
      const int tt = idx >> 9, l = (idx >> 3) & 63, i = idx & 7;
      const int k = (l >> 4) * 8 + i, n = tt * 16 + (l & 15);
      float v = 0.f;
      if (k < 16)       v = (n < 64) ? W_rbf0[k * 64 + n] : W_rbf1[k * 64 + (n - 64)];
      else if (k == 16) v = (n < 64) ? b_rbf0[n] : 0.f;   // bias row (A has 1.0 at k=16)
      ws16[B0_OFF + idx] = f2bf(v);
    }
  } else {
    // W3 fragments: W3[k][n] = W_lin[128+k][n], frag f = s*4+t
    // element W3[s*32+(l>>4)*8+i][t*16+(l&15)]
    for (int idx = t; idx < 4096; idx += 64) {
      const int f = idx >> 9, l = (idx >> 3) & 63, i = idx & 7;
      const int s = f >> 2, tt = f & 3;
      const int k = s * 32 + (l >> 4) * 8 + i, n = tt * 16 + (l & 15);
      ws16[W3_OFF + idx] = f2bf(W_lin[(128 + k) * 64 + n]);
    }
  }
}

// ---------------- main fused kernel ----------------
__global__ __launch_bounds__(256) void feats_main(
    const int* __restrict__ coords, const float* __restrict__ rbf,
    const int* __restrict__ node_is, const int* __restrict__ node_js,
    const unsigned short* __restrict__ ws16, float* __restrict__ out) {
  __shared__ __align__(16) unsigned short tab[TAB_U16_PAD];   // 25088 B (emb1|emb2, bf16)
  __shared__ __align__(16) unsigned short stage[4][16 * 72];  // 9216 B, per-wave rbf0 transpose

  const int tid = threadIdx.x;
  const int lane = tid & 63;
  const int wv = tid >> 6;
  const int g = lane >> 4;     // 16-lane group 0..3
  const int lm = lane & 15;

  {  // tables -> LDS (u32 copy)
    const uint32_t* src = (const uint32_t*)ws16;
    uint32_t* dst = (uint32_t*)tab;
    for (int i = tid; i < TAB_U16_PAD / 2; i += 256) dst[i] = src[i];
  }

  // B fragments held in registers for the whole kernel
  short8 b0f[8], w3f[2][4];
  {
    const short8* p = (const short8*)(ws16 + B0_OFF);
#pragma unroll
    for (int t = 0; t < 8; ++t) b0f[t] = p[t * 64 + lane];
    const short8* q = (const short8*)(ws16 + W3_OFF);
#pragma unroll
    for (int f = 0; f < 8; ++f) w3f[f >> 2][f & 3] = q[f * 64 + lane];
  }
  __syncthreads();

  float* out_e1 = out;
  float* out_e2 = out + (size_t)N_EDGES * H_NF;
  const f32x4 zf = {0.f, 0.f, 0.f, 0.f};
  unsigned short* st = &stage[wv][0];

  for (int tile = blockIdx.x * 4 + wv; tile < NTILES; tile += gridDim.x * 4) {
    const int ebase = tile << 4;
    const int e = ebase + lm;               // all groups replicate lanes 0..15
    const int ci = coords[node_is[e]];
    const int cj = coords[node_js[e]];

    // A fragment: A[row=lm][k=g*8+i]; k<16 = rbf, k==16 = 1.0 (bias), else 0
    short8 af;
    if (lane < 32) {
      const float4* rp = (const float4*)(rbf + (size_t)e * 16 + g * 8);
      const float4 v0 = rp[0], v1 = rp[1];
      af[0] = f2bf(v0.x); af[1] = f2bf(v0.y); af[2] = f2bf(v0.z); af[3] = f2bf(v0.w);
      af[4] = f2bf(v1.x); af[5] = f2bf(v1.y); af[6] = f2bf(v1.z); af[7] = f2bf(v1.w);
    } else {
      af = (short8){0, 0, 0, 0, 0, 0, 0, 0};
      if (lane < 48) af[0] = (short)0x3F80;  // g==2 -> k=16 -> 1.0f
    }

    // GEMM1: t = rbf_pad @ [W_rbf0+bias | W_rbf1]   (16 x 128)
    f32x4 t0v[4], t1v[4];
#pragma unroll
    for (int t = 0; t < 4; ++t)
      t0v[t] = __builtin_amdgcn_mfma_f32_16x16x32_bf16(af, b0f[t], zf, 0, 0, 0);
#pragma unroll
    for (int t = 0; t < 4; ++t)
      t1v[t] = __builtin_amdgcn_mfma_f32_16x16x32_bf16(af, b0f[4 + t], zf, 0, 0, 0);

    // swish -> per-wave LDS transpose (C layout: row=g*4+q, col=t*16+lm)
#pragma unroll
    for (int t = 0; t < 4; ++t)
#pragma unroll
      for (int q = 0; q < 4; ++q)
        st[(g * 4 + q) * 72 + t * 16 + lm] = f2bf(swish_f(t0v[t][q]));

    // rbf0 A-fragments: row=lm, k = s*32 + g*8 + i  (144B row stride -> aligned b128)
    const short8 a2_0 = *(const short8*)&st[lm * 72 + g * 8];
    const short8 a2_1 = *(const short8*)&st[lm * 72 + 32 + g * 8];

    // per-row vocab ids for this lane's 4 output rows
    int cia[4], cja[4];
#pragma unroll
    for (int q = 0; q < 4; ++q) {
      cia[q] = __shfl(ci, g * 4 + q, 64);
      cja[q] = __shfl(cj, g * 4 + q, 64);
    }

    // GEMM2 + epilogue
#pragma unroll
    for (int t = 0; t < 4; ++t) {
      f32x4 acc = __builtin_amdgcn_mfma_f32_16x16x32_bf16(a2_0, w3f[0][t], zf, 0, 0, 0);
      acc = __builtin_amdgcn_mfma_f32_16x16x32_bf16(a2_1, w3f[1][t], acc, 0, 0, 0);
      const int hp = t * 16 + lm;
#pragma unroll
      for (int q = 0; q < 4; ++q) {
        const float x = acc[q]
                      + bf2f(tab[cia[q] * TAB_STRIDE + hp])
                      + bf2f(tab[TAB2_OFF + cja[q] * TAB_STRIDE + hp]);
        const float e1 = swish_f(x);
        const float e2 = t1v[t][q] * e1;
        const size_t o = (size_t)(ebase + g * 4 + q) * 64 + hp;
        out_e1[o] = e1;
        out_e2[o] = e2;
      }
    }
  }
}

extern "C" void kernel_launch(void* const* d_in, const int* in_sizes, int n_in,
                              void* d_out, int out_size, void* d_ws, size_t ws_size,
                              hipStream_t stream) {
  const int* coords    = (const int*)d_in[0];
  const float* rbf     = (const float*)d_in[1];
  const int* node_is   = (const int*)d_in[2];
  const int* node_js   = (const int*)d_in[3];
  const float* emb_W   = (const float*)d_in[4];
  const float* W_rbf0  = (const float*)d_in[5];
  const float* b_rbf0  = (const float*)d_in[6];
  const float* W_lin   = (const float*)d_in[7];
  const float* b_lin   = (const float*)d_in[8];
  const float* W_rbf1  = (const float*)d_in[9];
  unsigned short* ws16 = (unsigned short*)d_ws;
  float* out           = (float*)d_out;

  hipLaunchKernelGGL(feats_prep, dim3(VOCAB + 2), dim3(64), 0, stream,
                     emb_W, W_rbf0, b_rbf0, W_lin, b_lin, W_rbf1, ws16);
  hipLaunchKernelGGL(feats_main, dim3(1024), dim3(256), 0, stream,
                     coords, rbf, node_is, node_js, ws16, out);
}